// Round 6
// baseline (270.137 us; speedup 1.0000x reference)
//
#include <hip/hip_runtime.h>
#include <math.h>

// Problem constants (MoEGate: B=4,T=4096,C=2048,E=64,K=8)
#define NTOK   16384
#define CDIM   2048
#define NEXP   64
#define TOPK   8
#define GBLK   256           // fused kernel grid (64 tokens per block)

typedef _Float16 f16x8 __attribute__((ext_vector_type(8)));
typedef float    f32x4 __attribute__((ext_vector_type(4)));

// ============================================================================
// Kernel 1: pack W[64][2048] fp32 into f16 hi/lo images in MFMA B-fragment
// order. Entry t = ((s*4 + nt)*64 + lane): 8 f16 for (expert = nt*16+(lane&15),
// k = s*32 + (lane>>4)*8 + j). GEMM lane then loads one contiguous 16B chunk.
// ============================================================================
__global__ __launch_bounds__(256) void pack_w16_kernel(
    const float* __restrict__ W,
    _Float16* __restrict__ Wh, _Float16* __restrict__ Wl)
{
    int t    = blockIdx.x * 256 + threadIdx.x;   // 0..16383
    int lane = t & 63;
    int nt   = (t >> 6) & 3;
    int s    = t >> 8;                           // k32-step, 0..63
    int e    = nt * 16 + (lane & 15);
    int k    = s * 32 + (lane >> 4) * 8;
    const float* src = W + (size_t)e * CDIM + k;
    #pragma unroll
    for (int j = 0; j < 8; j++) {
        float x = src[j];
        _Float16 h = (_Float16)x;                // rte
        Wh[(size_t)t * 8 + j] = h;
        Wl[(size_t)t * 8 + j] = (_Float16)(x - (float)h);
    }
}

// One f16-split MFMA step: 32 k-elements, all 4 expert tiles (12 MFMAs).
__device__ __forceinline__ void mfma_step(
    const float4 v0, const float4 v1,
    const f16x8* __restrict__ bh, const f16x8* __restrict__ bl,
    f32x4* __restrict__ acc)
{
    float xr[8] = {v0.x, v0.y, v0.z, v0.w, v1.x, v1.y, v1.z, v1.w};
    f16x8 ah, al;
    #pragma unroll
    for (int j = 0; j < 8; j++) {
        _Float16 h = (_Float16)xr[j];
        ah[j] = h;
        al[j] = (_Float16)(xr[j] - (float)h);    // exact residual
    }
    #pragma unroll
    for (int nt = 0; nt < 4; nt++) {
        acc[nt] = __builtin_amdgcn_mfma_f32_16x16x32_f16(ah, bh[nt], acc[nt], 0, 0, 0);
        acc[nt] = __builtin_amdgcn_mfma_f32_16x16x32_f16(al, bh[nt], acc[nt], 0, 0, 0);
        acc[nt] = __builtin_amdgcn_mfma_f32_16x16x32_f16(ah, bl[nt], acc[nt], 0, 0, 0);
    }
}

// ============================================================================
// Kernel 2 (FUSED): full-K f16-split MFMA GEMM + in-register top-8 + sigmoid
// + normalize + per-block masked counts. Wave = 16 tokens x 64 experts,
// K=2048 (64 s-steps) with 2-deep parity prefetch (x from HBM, B frags from
// L2-hot packed images). Logits never leave registers: C-layout lane group
// q*16..q*16+15 holds token q*4+r's 64 experts as acc[nt][r]; top-8 via
// 16-lane shfl_xor argmax (strict >, lowest index wins ties = JAX).
// ZERO global atomics: LDS counts -> blockcnt[GBLK][64].
// ============================================================================
__global__ __launch_bounds__(256, 4) void gate_fused_kernel(
    const float* __restrict__ x,       // [NTOK][CDIM]
    const _Float16* __restrict__ Wh,   // packed image, 256 KB
    const _Float16* __restrict__ Wl,   // packed image, 256 KB
    const int*   __restrict__ mask,    // [NTOK]
    const float* __restrict__ gbias,   // [NEXP]
    const float* __restrict__ ebias,   // [NEXP]
    float*       __restrict__ out,     // [2*NTOK*TOPK + 1]
    float*       __restrict__ blockcnt)// [GBLK][NEXP]
{
    __shared__ unsigned int cnt[NEXP];
    const int tid  = threadIdx.x;
    const int lane = tid & 63;
    const int wid  = tid >> 6;
    if (tid < NEXP) cnt[tid] = 0u;
    __syncthreads();

    const int tok0 = blockIdx.x * 64 + wid * 16;
    const int col  = lane & 15;                  // expert-within-tile / token col
    const int q    = lane >> 4;                  // quad
    const float* xp = x + (size_t)(tok0 + col) * CDIM + q * 8;
    const f16x8* bhp = (const f16x8*)Wh + lane;  // + s*256 + nt*64
    const f16x8* blp = (const f16x8*)Wl + lane;

    f32x4 acc[4];
    #pragma unroll
    for (int nt = 0; nt < 4; nt++) acc[nt] = (f32x4){0.f, 0.f, 0.f, 0.f};

    // ---- software-pipelined K loop: sets 0/1, prefetch one step ahead
    float4 a0v0, a0v1, a1v0, a1v1;
    f16x8 b0h[4], b0l[4], b1h[4], b1l[4];

    a0v0 = *(const float4*)(xp);
    a0v1 = *(const float4*)(xp + 4);
    #pragma unroll
    for (int nt = 0; nt < 4; nt++) { b0h[nt] = bhp[nt * 64]; b0l[nt] = blp[nt * 64]; }

    for (int s = 0; s < 64; s += 2) {
        // prefetch s+1 into set1 (s <= 62 so s+1 valid)
        a1v0 = *(const float4*)(xp + (s + 1) * 32);
        a1v1 = *(const float4*)(xp + (s + 1) * 32 + 4);
        #pragma unroll
        for (int nt = 0; nt < 4; nt++) {
            b1h[nt] = bhp[(s + 1) * 256 + nt * 64];
            b1l[nt] = blp[(s + 1) * 256 + nt * 64];
        }
        mfma_step(a0v0, a0v1, b0h, b0l, acc);

        // prefetch s+2 into set0 (clamp: redundant reload of 63 on last iter)
        const int s2 = (s + 2 < 64) ? (s + 2) : 63;
        a0v0 = *(const float4*)(xp + s2 * 32);
        a0v1 = *(const float4*)(xp + s2 * 32 + 4);
        #pragma unroll
        for (int nt = 0; nt < 4; nt++) {
            b0h[nt] = bhp[s2 * 256 + nt * 64];
            b0l[nt] = blp[s2 * 256 + nt * 64];
        }
        mfma_step(a1v0, a1v1, b1h, b1l, acc);
    }

    // ---- epilogue: per r (token = tok0 + q*4 + r), 16-lane top-8
    float gb[4], eb[4];
    #pragma unroll
    for (int nt = 0; nt < 4; nt++) {
        gb[nt] = gbias[nt * 16 + col];
        eb[nt] = ebias[nt * 16 + col];
    }

    #pragma unroll
    for (int r = 0; r < 4; r++) {
        const int t = tok0 + q * 4 + r;
        float z[4], sel[4];
        #pragma unroll
        for (int nt = 0; nt < 4; nt++) {
            z[nt]   = acc[nt][r] + gb[nt];
            sel[nt] = z[nt] + eb[nt];
        }

        int idxs[TOPK]; float probs[TOPK]; float psum = 0.f;
        #pragma unroll
        for (int rr = 0; rr < TOPK; rr++) {
            float bv = -INFINITY, bz = 0.f; int bidx = 1 << 30;
            #pragma unroll
            for (int nt = 0; nt < 4; nt++)
                if (sel[nt] > bv) { bv = sel[nt]; bz = z[nt]; bidx = nt * 16 + col; }
            #pragma unroll
            for (int m = 1; m < 16; m <<= 1) {   // xor<16 stays in 16-lane group
                float ov = __shfl_xor(bv, m);
                float oz = __shfl_xor(bz, m);
                int   oi = __shfl_xor(bidx, m);
                if (ov > bv || (ov == bv && oi < bidx)) { bv = ov; bz = oz; bidx = oi; }
            }
            idxs[rr] = bidx;
            float p = 1.f / (1.f + expf(-bz));
            probs[rr] = p; psum += p;
            if ((bidx & 15) == col) sel[bidx >> 4] = -INFINITY;   // mark used
        }
        float inv = 1.f / psum;
        if (col < TOPK) {
            out[(size_t)t * TOPK + col] = (float)idxs[col];
            out[(size_t)NTOK * TOPK + (size_t)t * TOPK + col] = probs[col] * inv;
            if (mask[t] != 0) atomicAdd(&cnt[idxs[col]], 1u);
        }
    }
    __syncthreads();
    if (tid < NEXP)
        blockcnt[(size_t)blockIdx.x * NEXP + tid] = (float)cnt[tid];
}

// ============================================================================
// Kernel 3: tree-sum per-block counts -> maxvio. One block, 256 threads.
// ============================================================================
__global__ __launch_bounds__(256) void finalize_kernel(
    const float* __restrict__ blockcnt, float* __restrict__ out)
{
    __shared__ float ps[4][NEXP];
    const int t = threadIdx.x;
    const int e = t & 63, c = t >> 6;
    float s = 0.f;
    #pragma unroll 8
    for (int b = 0; b < GBLK / 4; b++)
        s += blockcnt[(size_t)(c * (GBLK / 4) + b) * NEXP + e];
    ps[c][e] = s;
    __syncthreads();
    if (t < 64) {
        float tot = ps[0][t] + ps[1][t] + ps[2][t] + ps[3][t];
        float mx = tot, sm = tot;
        #pragma unroll
        for (int o = 32; o > 0; o >>= 1) {
            mx = fmaxf(mx, __shfl_down(mx, o));
            sm += __shfl_down(sm, o);
        }
        if (t == 0) {
            float avg = sm / (float)NEXP;
            out[2 * NTOK * TOPK] = (mx - avg) / (avg + 1e-5f);
        }
    }
}

// ============================================================================
// Fallback for tiny workspace: R1 fused fp32 kernel (known-correct).
// ============================================================================
__global__ __launch_bounds__(256) void fused_fallback_kernel(
    const float* __restrict__ x, const int* __restrict__ mask,
    const float* __restrict__ W, const float* __restrict__ gbias,
    const float* __restrict__ ebias, float* __restrict__ out,
    unsigned int* __restrict__ counts)
{
    __shared__ float As[64][36];
    __shared__ float Bs[64][36];
    __shared__ float Lg[64][NEXP + 1];
    __shared__ float s_gb[NEXP], s_eb[NEXP];
    __shared__ unsigned int s_cnt[NEXP];
    const int tid = threadIdx.x;
    const int tx = tid & 15, ty = tid >> 4;
    const int m0 = blockIdx.x * 64;
    if (tid < NEXP) { s_gb[tid] = gbias[tid]; s_eb[tid] = ebias[tid]; s_cnt[tid] = 0u; }
    float acc[4][4] = {};
    for (int kb = 0; kb < CDIM; kb += 32) {
        __syncthreads();
        #pragma unroll
        for (int p = 0; p < 2; p++) {
            int lin = tid + p * 256; int m = lin >> 3; int c4 = (lin & 7) << 2;
            *(float4*)&As[m][c4] = *(const float4*)&x[(size_t)(m0 + m) * CDIM + kb + c4];
            *(float4*)&Bs[m][c4] = *(const float4*)&W[(size_t)m * CDIM + kb + c4];
        }
        __syncthreads();
        #pragma unroll
        for (int k4 = 0; k4 < 32; k4 += 4) {
            float4 a[4], b[4];
            #pragma unroll
            for (int i = 0; i < 4; i++) a[i] = *(const float4*)&As[ty * 4 + i][k4];
            #pragma unroll
            for (int j = 0; j < 4; j++) b[j] = *(const float4*)&Bs[tx * 4 + j][k4];
            #pragma unroll
            for (int i = 0; i < 4; i++)
                #pragma unroll
                for (int j = 0; j < 4; j++)
                    acc[i][j] += a[i].x * b[j].x + a[i].y * b[j].y
                               + a[i].z * b[j].z + a[i].w * b[j].w;
        }
    }
    __syncthreads();
    #pragma unroll
    for (int i = 0; i < 4; i++)
        #pragma unroll
        for (int j = 0; j < 4; j++)
            Lg[ty * 4 + i][tx * 4 + j] = acc[i][j] + s_gb[tx * 4 + j];
    __syncthreads();
    if (tid < 64) {
        const int g = m0 + tid;
        unsigned long long used = 0ull;
        int idxs[TOPK]; float probs[TOPK]; float psum = 0.f;
        #pragma unroll
        for (int k = 0; k < TOPK; k++) {
            float best = -INFINITY; int bi = 0;
            for (int n = 0; n < NEXP; n++) {
                if ((used >> n) & 1ull) continue;
                float vv = Lg[tid][n] + s_eb[n];
                if (vv > best) { best = vv; bi = n; }
            }
            used |= (1ull << bi);
            idxs[k] = bi;
            float p = 1.f / (1.f + expf(-Lg[tid][bi]));
            probs[k] = p; psum += p;
        }
        float inv = 1.f / psum;
        #pragma unroll
        for (int k = 0; k < TOPK; k++) {
            out[(size_t)g * TOPK + k] = (float)idxs[k];
            out[(size_t)NTOK * TOPK + (size_t)g * TOPK + k] = probs[k] * inv;
        }
        if (mask[g] != 0)
            #pragma unroll
            for (int k = 0; k < TOPK; k++) atomicAdd(&s_cnt[idxs[k]], 1u);
    }
    __syncthreads();
    if (tid < NEXP && s_cnt[tid] != 0u) atomicAdd(&counts[tid], s_cnt[tid]);
}

__global__ void finalize_atomic_kernel(const unsigned int* __restrict__ counts,
                                       float* __restrict__ out)
{
    const int t = threadIdx.x;
    float c  = (float)counts[t];
    float mx = c, sm = c;
    #pragma unroll
    for (int o = 32; o > 0; o >>= 1) {
        mx = fmaxf(mx, __shfl_down(mx, o));
        sm += __shfl_down(sm, o);
    }
    if (t == 0) {
        float avg = sm / (float)NEXP;
        out[2 * NTOK * TOPK] = (mx - avg) / (avg + 1e-5f);
    }
}

extern "C" void kernel_launch(void* const* d_in, const int* in_sizes, int n_in,
                              void* d_out, int out_size, void* d_ws, size_t ws_size,
                              hipStream_t stream)
{
    const float* x     = (const float*)d_in[0];
    const int*   mask  = (const int*)  d_in[1];
    const float* W     = (const float*)d_in[2];
    const float* gbias = (const float*)d_in[3];
    const float* ebias = (const float*)d_in[4];
    float* out = (float*)d_out;

    // ws layout: [Wh 256KB][Wl 256KB][blockcnt 64KB]
    const size_t whB  = (size_t)NEXP * CDIM * sizeof(_Float16);   // 256 KB
    const size_t bcB  = (size_t)GBLK * NEXP * sizeof(float);      // 64 KB
    const size_t need = 2 * whB + bcB;

    if (ws_size >= need) {
        _Float16* Wh = (_Float16*)d_ws;
        _Float16* Wl = (_Float16*)((char*)d_ws + whB);
        float* blockcnt = (float*)((char*)d_ws + 2 * whB);

        pack_w16_kernel<<<64, 256, 0, stream>>>(W, Wh, Wl);
        gate_fused_kernel<<<GBLK, 256, 0, stream>>>(x, Wh, Wl, mask, gbias, ebias, out, blockcnt);
        finalize_kernel<<<1, 256, 0, stream>>>(blockcnt, out);
        return;
    }

    // Fallback: fused fp32 kernel + global-atomic counts
    unsigned int* counts = (unsigned int*)d_ws;
    hipMemsetAsync(d_ws, 0, NEXP * sizeof(unsigned int), stream);
    fused_fallback_kernel<<<NTOK / 64, 256, 0, stream>>>(x, mask, W, gbias, ebias, out, counts);
    finalize_atomic_kernel<<<1, 64, 0, stream>>>(counts, out);
}

// Round 7
// 239.479 us; speedup vs baseline: 1.1280x; 1.1280x over previous
//
#include <hip/hip_runtime.h>
#include <math.h>

// Problem constants (MoEGate: B=4,T=4096,C=2048,E=64,K=8)
#define NTOK   16384
#define CDIM   2048
#define NEXP   64
#define TOPK   8
#define GBLK   1024          // fused kernel grid: 16 tokens per block

typedef _Float16 f16x8 __attribute__((ext_vector_type(8)));
typedef float    f32x4 __attribute__((ext_vector_type(4)));

// ============================================================================
// Kernel 1: pack W[64][2048] fp32 into f16 hi/lo images in MFMA B-fragment
// order. Entry t = ((s*4 + nt)*64 + lane): 8 f16 for (expert = nt*16+(lane&15),
// k = s*32 + (lane>>4)*8 + j). GEMM lane then loads one contiguous 16B chunk.
// ============================================================================
__global__ __launch_bounds__(256) void pack_w16_kernel(
    const float* __restrict__ W,
    _Float16* __restrict__ Wh, _Float16* __restrict__ Wl)
{
    int t    = blockIdx.x * 256 + threadIdx.x;   // 0..16383
    int lane = t & 63;
    int nt   = (t >> 6) & 3;
    int s    = t >> 8;                           // k32-step, 0..63
    int e    = nt * 16 + (lane & 15);
    int k    = s * 32 + (lane >> 4) * 8;
    const float* src = W + (size_t)e * CDIM + k;
    #pragma unroll
    for (int j = 0; j < 8; j++) {
        float x = src[j];
        _Float16 h = (_Float16)x;                // rte
        Wh[(size_t)t * 8 + j] = h;
        Wl[(size_t)t * 8 + j] = (_Float16)(x - (float)h);
    }
}

// One f16-split MFMA step: 32 k-elements, all 4 expert tiles (12 MFMAs).
__device__ __forceinline__ void mfma_step(
    const float4 v0, const float4 v1,
    const f16x8* __restrict__ bh, const f16x8* __restrict__ bl,
    f32x4* __restrict__ acc)
{
    float xr[8] = {v0.x, v0.y, v0.z, v0.w, v1.x, v1.y, v1.z, v1.w};
    f16x8 ah, al;
    #pragma unroll
    for (int j = 0; j < 8; j++) {
        _Float16 h = (_Float16)xr[j];
        ah[j] = h;
        al[j] = (_Float16)(xr[j] - (float)h);    // exact residual
    }
    #pragma unroll
    for (int nt = 0; nt < 4; nt++) {
        acc[nt] = __builtin_amdgcn_mfma_f32_16x16x32_f16(ah, bh[nt], acc[nt], 0, 0, 0);
        acc[nt] = __builtin_amdgcn_mfma_f32_16x16x32_f16(al, bh[nt], acc[nt], 0, 0, 0);
        acc[nt] = __builtin_amdgcn_mfma_f32_16x16x32_f16(ah, bl[nt], acc[nt], 0, 0, 0);
    }
}

// ============================================================================
// Kernel 2 (FUSED, in-block k-split): block = 4 waves x SAME 16 tokens;
// wave w covers k-slice [w*512, (w+1)*512) (16 s-steps). Grid = NTOK/16 =
// 1024 blocks -> 4 blocks/CU, 16 waves/CU (TLP hides load latency; R6's
// 1-wave/SIMD starvation fixed). Waves meet in 16 KB LDS; wave 0 sums
// w-ascending (same order as R4/R5 verified reduce), then the verified
// 16-lane shfl_xor top-8 epilogue (strict >, lowest index wins ties = JAX).
// ZERO global atomics: LDS counts -> blockcnt[GBLK][64].
// ============================================================================
__global__ __launch_bounds__(256, 4) void gate_fused_kernel(
    const float* __restrict__ x,       // [NTOK][CDIM]
    const _Float16* __restrict__ Wh,   // packed image, 256 KB (L2-hot)
    const _Float16* __restrict__ Wl,   // packed image, 256 KB (L2-hot)
    const int*   __restrict__ mask,    // [NTOK]
    const float* __restrict__ gbias,   // [NEXP]
    const float* __restrict__ ebias,   // [NEXP]
    float*       __restrict__ out,     // [2*NTOK*TOPK + 1]
    float*       __restrict__ blockcnt)// [GBLK][NEXP]
{
    __shared__ f32x4 sacc[4][64][4];   // [wave][lane][nt]
    __shared__ unsigned int cnt[NEXP];
    const int tid  = threadIdx.x;
    const int lane = tid & 63;
    const int wid  = tid >> 6;
    if (tid < NEXP) cnt[tid] = 0u;     // wave 0 inits; only wave 0 uses cnt

    const int tok0 = blockIdx.x * 16;
    const int col  = lane & 15;        // token row for A / expert col for C
    const int q    = lane >> 4;        // quad
    const float* xp = x + (size_t)(tok0 + col) * CDIM + wid * 512 + q * 8;
    const f16x8* bhp = (const f16x8*)Wh + (size_t)wid * 16 * 256 + lane;
    const f16x8* blp = (const f16x8*)Wl + (size_t)wid * 16 * 256 + lane;

    f32x4 acc[4];
    #pragma unroll
    for (int nt = 0; nt < 4; nt++) acc[nt] = (f32x4){0.f, 0.f, 0.f, 0.f};

    #pragma unroll 2
    for (int s = 0; s < 16; s++) {
        float4 v0 = *(const float4*)(xp + s * 32);
        float4 v1 = *(const float4*)(xp + s * 32 + 4);
        f16x8 bh[4], bl[4];
        #pragma unroll
        for (int nt = 0; nt < 4; nt++) {
            bh[nt] = bhp[s * 256 + nt * 64];
            bl[nt] = blp[s * 256 + nt * 64];
        }
        mfma_step(v0, v1, bh, bl, acc);
    }

    // ---- stage partial accumulators to LDS, wave 0 combines
    #pragma unroll
    for (int nt = 0; nt < 4; nt++) sacc[wid][lane][nt] = acc[nt];
    __syncthreads();

    if (wid == 0) {
        f32x4 zv[4];
        #pragma unroll
        for (int nt = 0; nt < 4; nt++)
            zv[nt] = sacc[0][lane][nt] + sacc[1][lane][nt]
                   + sacc[2][lane][nt] + sacc[3][lane][nt];   // w-ascending order

        float gb[4], eb[4];
        #pragma unroll
        for (int nt = 0; nt < 4; nt++) {
            gb[nt] = gbias[nt * 16 + col];
            eb[nt] = ebias[nt * 16 + col];
        }

        #pragma unroll
        for (int r = 0; r < 4; r++) {
            const int t = tok0 + q * 4 + r;     // C layout: row = q*4 + reg
            float z[4], sel[4];
            #pragma unroll
            for (int nt = 0; nt < 4; nt++) {
                z[nt]   = zv[nt][r] + gb[nt];
                sel[nt] = z[nt] + eb[nt];
            }

            int idxs[TOPK]; float probs[TOPK]; float psum = 0.f;
            #pragma unroll
            for (int rr = 0; rr < TOPK; rr++) {
                float bv = -INFINITY, bz = 0.f; int bidx = 1 << 30;
                #pragma unroll
                for (int nt = 0; nt < 4; nt++)
                    if (sel[nt] > bv) { bv = sel[nt]; bz = z[nt]; bidx = nt * 16 + col; }
                #pragma unroll
                for (int m = 1; m < 16; m <<= 1) {   // xor<16 stays in 16-lane group
                    float ov = __shfl_xor(bv, m);
                    float oz = __shfl_xor(bz, m);
                    int   oi = __shfl_xor(bidx, m);
                    if (ov > bv || (ov == bv && oi < bidx)) { bv = ov; bz = oz; bidx = oi; }
                }
                idxs[rr] = bidx;
                float p = 1.f / (1.f + expf(-bz));
                probs[rr] = p; psum += p;
                if ((bidx & 15) == col) sel[bidx >> 4] = -INFINITY;   // mark used
            }
            float inv = 1.f / psum;
            if (col < TOPK) {
                out[(size_t)t * TOPK + col] = (float)idxs[col];
                out[(size_t)NTOK * TOPK + (size_t)t * TOPK + col] = probs[col] * inv;
                if (mask[t] != 0) atomicAdd(&cnt[idxs[col]], 1u);
            }
        }
        blockcnt[(size_t)blockIdx.x * NEXP + lane] = (float)cnt[lane];
    }
}

// ============================================================================
// Kernel 3: tree-sum per-block counts -> maxvio. One block, 256 threads.
// ============================================================================
__global__ __launch_bounds__(256) void finalize_kernel(
    const float* __restrict__ blockcnt, float* __restrict__ out)
{
    __shared__ float ps[4][NEXP];
    const int t = threadIdx.x;
    const int e = t & 63, c = t >> 6;
    float s = 0.f;
    #pragma unroll 8
    for (int b = 0; b < GBLK / 4; b++)
        s += blockcnt[(size_t)(c * (GBLK / 4) + b) * NEXP + e];
    ps[c][e] = s;
    __syncthreads();
    if (t < 64) {
        float tot = ps[0][t] + ps[1][t] + ps[2][t] + ps[3][t];
        float mx = tot, sm = tot;
        #pragma unroll
        for (int o = 32; o > 0; o >>= 1) {
            mx = fmaxf(mx, __shfl_down(mx, o));
            sm += __shfl_down(sm, o);
        }
        if (t == 0) {
            float avg = sm / (float)NEXP;
            out[2 * NTOK * TOPK] = (mx - avg) / (avg + 1e-5f);
        }
    }
}

// ============================================================================
// Fallback for tiny workspace: R1 fused fp32 kernel (known-correct).
// ============================================================================
__global__ __launch_bounds__(256) void fused_fallback_kernel(
    const float* __restrict__ x, const int* __restrict__ mask,
    const float* __restrict__ W, const float* __restrict__ gbias,
    const float* __restrict__ ebias, float* __restrict__ out,
    unsigned int* __restrict__ counts)
{
    __shared__ float As[64][36];
    __shared__ float Bs[64][36];
    __shared__ float Lg[64][NEXP + 1];
    __shared__ float s_gb[NEXP], s_eb[NEXP];
    __shared__ unsigned int s_cnt[NEXP];
    const int tid = threadIdx.x;
    const int tx = tid & 15, ty = tid >> 4;
    const int m0 = blockIdx.x * 64;
    if (tid < NEXP) { s_gb[tid] = gbias[tid]; s_eb[tid] = ebias[tid]; s_cnt[tid] = 0u; }
    float acc[4][4] = {};
    for (int kb = 0; kb < CDIM; kb += 32) {
        __syncthreads();
        #pragma unroll
        for (int p = 0; p < 2; p++) {
            int lin = tid + p * 256; int m = lin >> 3; int c4 = (lin & 7) << 2;
            *(float4*)&As[m][c4] = *(const float4*)&x[(size_t)(m0 + m) * CDIM + kb + c4];
            *(float4*)&Bs[m][c4] = *(const float4*)&W[(size_t)m * CDIM + kb + c4];
        }
        __syncthreads();
        #pragma unroll
        for (int k4 = 0; k4 < 32; k4 += 4) {
            float4 a[4], b[4];
            #pragma unroll
            for (int i = 0; i < 4; i++) a[i] = *(const float4*)&As[ty * 4 + i][k4];
            #pragma unroll
            for (int j = 0; j < 4; j++) b[j] = *(const float4*)&Bs[tx * 4 + j][k4];
            #pragma unroll
            for (int i = 0; i < 4; i++)
                #pragma unroll
                for (int j = 0; j < 4; j++)
                    acc[i][j] += a[i].x * b[j].x + a[i].y * b[j].y
                               + a[i].z * b[j].z + a[i].w * b[j].w;
        }
    }
    __syncthreads();
    #pragma unroll
    for (int i = 0; i < 4; i++)
        #pragma unroll
        for (int j = 0; j < 4; j++)
            Lg[ty * 4 + i][tx * 4 + j] = acc[i][j] + s_gb[tx * 4 + j];
    __syncthreads();
    if (tid < 64) {
        const int g = m0 + tid;
        unsigned long long used = 0ull;
        int idxs[TOPK]; float probs[TOPK]; float psum = 0.f;
        #pragma unroll
        for (int k = 0; k < TOPK; k++) {
            float best = -INFINITY; int bi = 0;
            for (int n = 0; n < NEXP; n++) {
                if ((used >> n) & 1ull) continue;
                float vv = Lg[tid][n] + s_eb[n];
                if (vv > best) { best = vv; bi = n; }
            }
            used |= (1ull << bi);
            idxs[k] = bi;
            float p = 1.f / (1.f + expf(-Lg[tid][bi]));
            probs[k] = p; psum += p;
        }
        float inv = 1.f / psum;
        #pragma unroll
        for (int k = 0; k < TOPK; k++) {
            out[(size_t)g * TOPK + k] = (float)idxs[k];
            out[(size_t)NTOK * TOPK + (size_t)g * TOPK + k] = probs[k] * inv;
        }
        if (mask[g] != 0)
            #pragma unroll
            for (int k = 0; k < TOPK; k++) atomicAdd(&s_cnt[idxs[k]], 1u);
    }
    __syncthreads();
    if (tid < NEXP && s_cnt[tid] != 0u) atomicAdd(&counts[tid], s_cnt[tid]);
}

__global__ void finalize_atomic_kernel(const unsigned int* __restrict__ counts,
                                       float* __restrict__ out)
{
    const int t = threadIdx.x;
    float c  = (float)counts[t];
    float mx = c, sm = c;
    #pragma unroll
    for (int o = 32; o > 0; o >>= 1) {
        mx = fmaxf(mx, __shfl_down(mx, o));
        sm += __shfl_down(sm, o);
    }
    if (t == 0) {
        float avg = sm / (float)NEXP;
        out[2 * NTOK * TOPK] = (mx - avg) / (avg + 1e-5f);
    }
}

extern "C" void kernel_launch(void* const* d_in, const int* in_sizes, int n_in,
                              void* d_out, int out_size, void* d_ws, size_t ws_size,
                              hipStream_t stream)
{
    const float* x     = (const float*)d_in[0];
    const int*   mask  = (const int*)  d_in[1];
    const float* W     = (const float*)d_in[2];
    const float* gbias = (const float*)d_in[3];
    const float* ebias = (const float*)d_in[4];
    float* out = (float*)d_out;

    // ws layout: [Wh 256KB][Wl 256KB][blockcnt 256KB]
    const size_t whB  = (size_t)NEXP * CDIM * sizeof(_Float16);   // 256 KB
    const size_t bcB  = (size_t)GBLK * NEXP * sizeof(float);      // 256 KB
    const size_t need = 2 * whB + bcB;

    if (ws_size >= need) {
        _Float16* Wh = (_Float16*)d_ws;
        _Float16* Wl = (_Float16*)((char*)d_ws + whB);
        float* blockcnt = (float*)((char*)d_ws + 2 * whB);

        pack_w16_kernel<<<64, 256, 0, stream>>>(W, Wh, Wl);
        gate_fused_kernel<<<GBLK, 256, 0, stream>>>(x, Wh, Wl, mask, gbias, ebias, out, blockcnt);
        finalize_kernel<<<1, 256, 0, stream>>>(blockcnt, out);
        return;
    }

    // Fallback: fused fp32 kernel + global-atomic counts
    unsigned int* counts = (unsigned int*)d_ws;
    hipMemsetAsync(d_ws, 0, NEXP * sizeof(unsigned int), stream);
    fused_fallback_kernel<<<NTOK / 64, 256, 0, stream>>>(x, mask, W, gbias, ebias, out, counts);
    finalize_atomic_kernel<<<1, 64, 0, stream>>>(counts, out);
}